// Round 3
// baseline (169.039 us; speedup 1.0000x reference)
//
#include <hip/hip_runtime.h>

typedef _Float16 f16x8 __attribute__((ext_vector_type(8)));
typedef float f32x4 __attribute__((ext_vector_type(4)));

#define EMB 768
#define LQ 128
#define LD 1024
#define NB 32

typedef const __attribute__((address_space(1))) char gas_char;
typedef __attribute__((address_space(3))) char las_char;

__device__ __forceinline__ void gload16(const void* g, void* l) {
    __builtin_amdgcn_global_load_lds((gas_char*)g, (las_char*)l, 16, 0, 0);
}

// ---- swizzles ----
// 128B-row-stride tiles (BK=64-hw): 8 chunks of 16B, XOR row&7  (round-2 proven)
#define SWZ(row, ch) ((row) * 64 + ((((ch) ^ ((row) & 7))) * 8))
// 64B-row-stride tiles (BK=32-hw): 4 chunks, XOR (row&3)^((row>>2)&3)  -> 2-way banks
#define SWZ32(row, c) ((row) * 32 + ((((c) ^ ((row) & 3) ^ (((row) >> 2) & 3))) * 8))

// ---------- f32 -> f16, 8 elems/thread ----------
__global__ void cvt8_kernel(const float* __restrict__ in, _Float16* __restrict__ out, int n8) {
    int i = blockIdx.x * 256 + threadIdx.x;
    if (i >= n8) return;
    const float4 a = ((const float4*)in)[2 * i];
    const float4 b = ((const float4*)in)[2 * i + 1];
    f16x8 o;
    o[0] = (_Float16)a.x; o[1] = (_Float16)a.y; o[2] = (_Float16)a.z; o[3] = (_Float16)a.w;
    o[4] = (_Float16)b.x; o[5] = (_Float16)b.y; o[6] = (_Float16)b.z; o[7] = (_Float16)b.w;
    ((f16x8*)out)[i] = o;
}

// ---------- VT[b][e][q] = query_embed[b][q][e] (f16) ----------
__global__ void make_vt_kernel(const float* __restrict__ Q, _Float16* __restrict__ VT) {
    int i = blockIdx.x * 256 + threadIdx.x;
    if (i >= NB * EMB * LQ) return;
    int q = i % LQ;
    int e = (i / LQ) % EMB;
    int b = i / (LQ * EMB);
    VT[i] = (_Float16)Q[((size_t)b * LQ + q) * EMB + e];
}

// ---------- projection GEMM, 256x256 tile, BK=32, ring-3 LDS, 8 waves ----------
// OUT[m,h] = relu(A[m,:] . B[h,:] + bias[h]) in f16. M = 36864 (doc||query rows).
// Schedule: per K-tile j (2 phases of 16 MFMA), stage K-tile j+2 into buf[(j+2)%3];
// counted vmcnt(4) once per K-tile; raw s_barrier; setprio around MFMA clusters.
__global__ __launch_bounds__(512, 2) void proj256_kernel(
    const _Float16* __restrict__ A, const _Float16* __restrict__ B,
    const float* __restrict__ bias, _Float16* __restrict__ OUT, int nrowblk) {
    extern __shared__ _Float16 smem[];  // 3 bufs x (A 8192 | B 8192) hw = 96 KB
    const int tid = threadIdx.x, wave = tid >> 6, lane = tid & 63;
    const int lr = lane & 15, lkg = lane >> 4;
    const int wr = wave >> 2, wc = wave & 3;  // 2 x 4 waves, wave tile 128x64

    // XCD swizzle: grid = nrowblk*3, contiguous chunk per XCD (nwg % 8 == 0)
    const int nwg = nrowblk * 3, cpx = nwg >> 3;
    const int bid = blockIdx.x;
    const int swz = (bid & 7) * cpx + (bid >> 3);
    const int rowblk = swz / 3, colblk = swz % 3;
    const int row0 = rowblk * 256, col0 = colblk * 256;

    const _Float16* gA = A + (size_t)row0 * EMB;
    const _Float16* gB = B + (size_t)col0 * EMB;

    // stage-source precompute: thread covers linear chunks {tid, 512+tid} of each 8192-hw unit
    const int sr0 = tid >> 2, sc = tid & 3;
    const int sig = (sr0 & 3) ^ ((sr0 >> 2) & 3);   // same for sr0+128
    const int scs = (sc ^ sig) * 8;                 // inverse-swizzled source chunk
    const _Float16* srcA0 = gA + (size_t)sr0 * EMB + scs;
    const _Float16* srcA1 = gA + (size_t)(sr0 + 128) * EMB + scs;
    const _Float16* srcB0 = gB + (size_t)sr0 * EMB + scs;
    const _Float16* srcB1 = gB + (size_t)(sr0 + 128) * EMB + scs;

#define STAGE_A(kt, bufi) { _Float16* d = smem + (bufi) * 16384 + wave * 512; \
        gload16(srcA0 + (kt) * 32, d); gload16(srcA1 + (kt) * 32, d + 4096); }
#define STAGE_B(kt, bufi) { _Float16* d = smem + (bufi) * 16384 + 8192 + wave * 512; \
        gload16(srcB0 + (kt) * 32, d); gload16(srcB1 + (kt) * 32, d + 4096); }

    f32x4 acc[8][4];
#pragma unroll
    for (int m = 0; m < 8; ++m)
#pragma unroll
        for (int n = 0; n < 4; ++n) acc[m][n] = (f32x4){0.f, 0.f, 0.f, 0.f};

    const int rdoff = ((lkg ^ (lr & 3) ^ ((lr >> 2) & 3)) * 8);  // swizzled read chunk

    // prologue: kt0 -> buf0, kt1 -> buf1; wait kt0 landed (leave kt1's 4 loads in flight)
    STAGE_A(0, 0); STAGE_B(0, 0); STAGE_A(1, 1); STAGE_B(1, 1);
    asm volatile("s_waitcnt vmcnt(4)" ::: "memory");
    __builtin_amdgcn_s_barrier();

    int bi = 0;
    for (int j = 0; j < 24; ++j) {
        const _Float16* bufA = smem + bi * 16384;
        const _Float16* bufB = bufA + 8192;
        int nb = bi + 2; if (nb >= 3) nb -= 3;
        f16x8 bf[4], af[4];
        // ---- phase A: bf + af(m0-3); stage A(j+2); 16 MFMA ----
#pragma unroll
        for (int n = 0; n < 4; ++n)
            bf[n] = *(const f16x8*)(bufB + (wc * 64 + n * 16 + lr) * 32 + rdoff);
#pragma unroll
        for (int m = 0; m < 4; ++m)
            af[m] = *(const f16x8*)(bufA + (wr * 128 + m * 16 + lr) * 32 + rdoff);
        if (j + 2 < 24) { STAGE_A(j + 2, nb); }
        __builtin_amdgcn_s_barrier();
        asm volatile("s_waitcnt lgkmcnt(0)" ::: "memory");
        __builtin_amdgcn_sched_barrier(0);
        __builtin_amdgcn_s_setprio(1);
#pragma unroll
        for (int m = 0; m < 4; ++m)
#pragma unroll
            for (int n = 0; n < 4; ++n)
                acc[m][n] = __builtin_amdgcn_mfma_f32_16x16x32_f16(af[m], bf[n], acc[m][n], 0, 0, 0);
        __builtin_amdgcn_s_setprio(0);
        __builtin_amdgcn_s_barrier();
        // ---- phase B: af(m4-7); stage B(j+2); vmcnt(4); 16 MFMA ----
#pragma unroll
        for (int m = 0; m < 4; ++m)
            af[m] = *(const f16x8*)(bufA + (wr * 128 + (m + 4) * 16 + lr) * 32 + rdoff);
        if (j + 2 < 24) { STAGE_B(j + 2, nb); }
        if (j + 3 < 24) { asm volatile("s_waitcnt vmcnt(4)" ::: "memory"); }
        else            { asm volatile("s_waitcnt vmcnt(0)" ::: "memory"); }
        __builtin_amdgcn_s_barrier();
        asm volatile("s_waitcnt lgkmcnt(0)" ::: "memory");
        __builtin_amdgcn_sched_barrier(0);
        __builtin_amdgcn_s_setprio(1);
#pragma unroll
        for (int m = 0; m < 4; ++m)
#pragma unroll
            for (int n = 0; n < 4; ++n)
                acc[m + 4][n] = __builtin_amdgcn_mfma_f32_16x16x32_f16(af[m], bf[n], acc[m + 4][n], 0, 0, 0);
        __builtin_amdgcn_s_setprio(0);
        __builtin_amdgcn_s_barrier();
        bi = (bi == 2) ? 0 : bi + 1;
    }

    // epilogue: bias + ReLU + f16 store
    const int crow = lkg * 4;
#pragma unroll
    for (int n = 0; n < 4; ++n) {
        const int gc = col0 + wc * 64 + n * 16 + lr;
        const float bv = bias[gc];
#pragma unroll
        for (int m = 0; m < 8; ++m) {
            const size_t gr = (size_t)row0 + wr * 128 + m * 16 + crow;
#pragma unroll
            for (int r = 0; r < 4; ++r) {
                float v = acc[m][n][r] + bv;
                OUT[(gr + r) * EMB + gc] = (_Float16)(v > 0.f ? v : 0.f);
            }
        }
    }
#undef STAGE_A
#undef STAGE_B
}

// ---------- attention: 64 doc rows/block, 4 waves, 48 KB LDS (2 blocks/CU) ----------
__global__ __launch_bounds__(256) void attn64_kernel(
    const _Float16* __restrict__ Do, const _Float16* __restrict__ Qo,
    const _Float16* __restrict__ VT, float* __restrict__ OUT) {
    __shared__ __align__(16) _Float16 smem[24576];  // dbuf x (D 4096 | Q 8192); P aliases after
    const int tid = threadIdx.x, wave = tid >> 6, lane = tid & 63;
    const int lr = lane & 15, lkg = lane >> 4;

    // batch-locality XCD swizzle: XCD x owns batches [x*4, x*4+4)
    const int l = blockIdx.x;             // 0..511
    const int x = l & 7, i = l >> 3;      // i: 0..63
    const int b = x * 4 + (i >> 4), dblk = i & 15;

    const _Float16* gd = Do + ((size_t)b * LD + dblk * 64) * EMB;
    const _Float16* gq = Qo + (size_t)b * LQ * EMB;

    f32x4 s[8];
#pragma unroll
    for (int n = 0; n < 8; ++n) s[n] = (f32x4){0.f, 0.f, 0.f, 0.f};

    // staging: D tile 64x64hw (2 loads/thr), Q tile 128x64hw (4 loads/thr)
#define STAGE_D(g, base) { \
    _Float16* lb = (base); \
    { int idx = tid;       int row = idx >> 3, ch = idx & 7; int lch = ch ^ (row & 7); \
      gload16((g) + (size_t)row * EMB + lch * 8, lb + (size_t)(wave * 64) * 8); } \
    { int idx = 256 + tid; int row = idx >> 3, ch = idx & 7; int lch = ch ^ (row & 7); \
      gload16((g) + (size_t)row * EMB + lch * 8, lb + (size_t)(256 + wave * 64) * 8); } }
#define STAGE_Q(g, base) { \
    _Float16* lb = (base); \
    _Pragma("unroll") \
    for (int it2 = 0; it2 < 4; ++it2) { \
      int idx = it2 * 256 + tid; int row = idx >> 3, ch = idx & 7; int lch = ch ^ (row & 7); \
      gload16((g) + (size_t)row * EMB + lch * 8, lb + (size_t)(it2 * 256 + wave * 64) * 8); } }

    STAGE_D(gd, smem);
    STAGE_Q(gq, smem + 4096);
    int cur = 0;
    for (int it = 0; it < 12; ++it) {
        __syncthreads();
        if (it < 11) {
            STAGE_D(gd + (it + 1) * 64, smem + (cur ^ 1) * 12288);
            STAGE_Q(gq + (it + 1) * 64, smem + (cur ^ 1) * 12288 + 4096);
        }
        const _Float16* sD = smem + cur * 12288;
        const _Float16* sQ = sD + 4096;
#pragma unroll
        for (int kk = 0; kk < 2; ++kk) {
            const int ch = kk * 4 + lkg;
            const f16x8 af = *(const f16x8*)(sD + SWZ(wave * 16 + lr, ch));
#pragma unroll
            for (int n = 0; n < 8; ++n) {
                const f16x8 bq = *(const f16x8*)(sQ + SWZ(n * 16 + lr, ch));
                s[n] = __builtin_amdgcn_mfma_f32_16x16x32_f16(af, bq, s[n], 0, 0, 0);
            }
        }
        cur ^= 1;
    }
    __syncthreads();  // staging reads done before P overwrites smem

    // exact softmax over 128 cols per doc row (16-lane-group shfl reduce), P -> LDS f16
    _Float16 (*P)[136] = (_Float16 (*)[136])smem;  // 272B stride -> 2-way (free)
    const int crow = lkg * 4;
#pragma unroll
    for (int r = 0; r < 4; ++r) {
        float mx = -1e30f;
#pragma unroll
        for (int n = 0; n < 8; ++n) mx = fmaxf(mx, s[n][r]);
#pragma unroll
        for (int off = 1; off < 16; off <<= 1) mx = fmaxf(mx, __shfl_xor(mx, off));
        float p[8], sum = 0.f;
#pragma unroll
        for (int n = 0; n < 8; ++n) { p[n] = __expf(s[n][r] - mx); sum += p[n]; }
#pragma unroll
        for (int off = 1; off < 16; off <<= 1) sum += __shfl_xor(sum, off);
        const float inv = 1.f / sum;
        const int row = wave * 16 + crow + r;
#pragma unroll
        for (int n = 0; n < 8; ++n) P[row][n * 16 + lr] = (_Float16)(p[n] * inv);
    }
    __syncthreads();

    // PV: out[64,768] = P[64,128] . V ; B-operand VT[e][q] direct from L2
    const _Float16* vtb = VT + (size_t)b * EMB * LQ;
    const size_t dbase = (size_t)b * LD + dblk * 64 + wave * 16 + crow;
#pragma unroll 1
    for (int nc = 0; nc < 6; ++nc) {
        f32x4 o[8];
#pragma unroll
        for (int t = 0; t < 8; ++t) o[t] = (f32x4){0.f, 0.f, 0.f, 0.f};
#pragma unroll
        for (int ks = 0; ks < 4; ++ks) {
            const f16x8 am = *(const f16x8*)(&P[wave * 16 + lr][ks * 32 + lkg * 8]);
#pragma unroll
            for (int t = 0; t < 8; ++t) {
                const f16x8 bv = *(const f16x8*)(vtb + (size_t)(nc * 128 + t * 16 + lr) * LQ + ks * 32 + lkg * 8);
                o[t] = __builtin_amdgcn_mfma_f32_16x16x32_f16(am, bv, o[t], 0, 0, 0);
            }
        }
#pragma unroll
        for (int t = 0; t < 8; ++t) {
            const int e = nc * 128 + t * 16 + lr;
#pragma unroll
            for (int r = 0; r < 4; ++r)
                OUT[(dbase + r) * EMB + e] = o[t][r];
        }
    }
#undef STAGE_D
#undef STAGE_Q
}

extern "C" void kernel_launch(void* const* d_in, const int* in_sizes, int n_in,
                              void* d_out, int out_size, void* d_ws, size_t ws_size,
                              hipStream_t stream) {
    const float* doc   = (const float*)d_in[0];   // [32,1024,768]
    const float* query = (const float*)d_in[1];   // [32,128,768]
    const float* W     = (const float*)d_in[2];   // [768,768]
    const float* bias  = (const float*)d_in[3];   // [768]
    float* out = (float*)d_out;                   // [32,1024,768] f32

    const size_t nW  = (size_t)EMB * EMB;        // 589824
    const size_t nVT = (size_t)NB * EMB * LQ;    // 3145728
    const size_t nDo = (size_t)NB * LD * EMB;    // 25165824
    const size_t nQo = (size_t)NB * LQ * EMB;    // 3145728
    const size_t need = (nW + nVT + nDo + nQo) * sizeof(_Float16);  // ~64.1 MB
    if (ws_size < need) return;

    _Float16* W16 = (_Float16*)d_ws;
    _Float16* VT  = W16 + nW;
    _Float16* Do  = VT + nVT;    // Do || Qo contiguous: single proj output
    _Float16* Qo  = Do + nDo;

    // f16 copies of doc/query live in d_out (dead until attn writes it), CONTIGUOUS
    _Float16* doc16 = (_Float16*)d_out;
    _Float16* q16   = doc16 + nDo;

    cvt8_kernel<<<(int)(nDo / 8 / 256), 256, 0, stream>>>(doc, doc16, (int)(nDo / 8));
    cvt8_kernel<<<(int)(nQo / 8 / 256), 256, 0, stream>>>(query, q16, (int)(nQo / 8));
    cvt8_kernel<<<(int)(nW / 8 / 256), 256, 0, stream>>>(W, W16, (int)(nW / 8));
    make_vt_kernel<<<(int)(nVT / 256), 256, 0, stream>>>(query, VT);

    // merged projection: M = 32768 + 4096 = 36864 rows -> 144 row-blocks x 3 col-blocks
    const int nrowblk = (int)((nDo + nQo) / EMB / 256);  // 144
    hipFuncSetAttribute(reinterpret_cast<const void*>(&proj256_kernel),
                        hipFuncAttributeMaxDynamicSharedMemorySize, 98304);
    proj256_kernel<<<dim3(nrowblk * 3), 512, 98304, stream>>>(doc16, W16, bias, Do, nrowblk);

    attn64_kernel<<<dim3(NB * 16), 256, 0, stream>>>(Do, Qo, VT, out);
}